// Round 2
// baseline (239.823 us; speedup 1.0000x reference)
//
#include <hip/hip_runtime.h>
#include <hip/hip_bf16.h>

#define B_    2
#define N_    6400
#define CD_   128
#define CM_   64
#define SEG_  10
#define JSEG_ (N_ / SEG_)    // 640
#define JT_   64
#define NJT_  (JSEG_ / JT_)  // 10
#define NIT_  50             // i-tiles of 128 per batch (flash)

typedef __attribute__((ext_vector_type(8)))  short bf16x8;
typedef __attribute__((ext_vector_type(16))) float f32x16;

static __device__ __forceinline__ unsigned pack2bf(float a, float b) {
    // {lo16: bf16(a), hi16: bf16(b)} via round-half-up + byte-perm
    union { float f; unsigned u; } x, y; x.f = a; y.f = b;
    return __builtin_amdgcn_perm(y.u + 0x8000u, x.u + 0x8000u, 0x07060302u);
}

static __device__ __forceinline__ unsigned cvtpk_bf16(float a, float b) {
    // {lo16: bf16(a), hi16: bf16(b)}, RNE — single VALU op
    unsigned r;
    asm("v_cvt_pk_bf16_f32 %0, %1, %2" : "=v"(r) : "v"(a), "v"(b));
    return r;
}

// ---------------- fused projections ----------------
// blocks [0,400): q from z_hsi (C=128); [400,800): k,v from z_msi (C=64)
// qb[b][i][o], kb[b][j][o], vb[b][o][j]  (bf16)
__global__ __launch_bounds__(256, 4)
void proj2(const float* __restrict__ zh, const float* __restrict__ zm,
           const float* __restrict__ Wq, const float* __restrict__ bq,
           const float* __restrict__ Wk, const float* __restrict__ bk,
           const float* __restrict__ Wv, const float* __restrict__ bv,
           short* __restrict__ qb, short* __restrict__ kb, short* __restrict__ vb)
{
    __shared__ float zt[128 * 68];   // [c][i], stride 68 (16B-aligned rows)
    const int tid = threadIdx.x;
    int bid = blockIdx.x;
    const int qmode = bid < 400;
    if (!qmode) bid -= 400;
    const int b  = bid / 200;
    const int r  = bid % 200;
    const int i0 = (r >> 1) * 64;
    const int o0 = (r & 1) * 64;
    const int ig = tid & 15, og = tid >> 4;
    const int il = ig * 4;

    if (qmode) {
        const float* zsrc = zh + (size_t)b * CD_ * N_ + i0;
#pragma unroll
        for (int rep = 0; rep < 8; ++rep) {
            int idx = tid + rep * 256;
            int c = idx >> 4, f = idx & 15;
            *(float4*)&zt[c * 68 + f * 4] = *(const float4*)&zsrc[(size_t)c * N_ + f * 4];
        }
        __syncthreads();
        const float* wr0 = Wq + (size_t)(o0 + og * 4 + 0) * CD_;
        const float* wr1 = Wq + (size_t)(o0 + og * 4 + 1) * CD_;
        const float* wr2 = Wq + (size_t)(o0 + og * 4 + 2) * CD_;
        const float* wr3 = Wq + (size_t)(o0 + og * 4 + 3) * CD_;
        float acc[4][4];
#pragma unroll
        for (int oi = 0; oi < 4; ++oi) {
            float bb = bq[o0 + og * 4 + oi];
#pragma unroll
            for (int ri = 0; ri < 4; ++ri) acc[ri][oi] = bb;
        }
        for (int c4 = 0; c4 < 32; ++c4) {
            float4 w0 = *(const float4*)&wr0[c4 * 4];
            float4 w1 = *(const float4*)&wr1[c4 * 4];
            float4 w2 = *(const float4*)&wr2[c4 * 4];
            float4 w3 = *(const float4*)&wr3[c4 * 4];
            float ww[4][4] = {{w0.x,w1.x,w2.x,w3.x},{w0.y,w1.y,w2.y,w3.y},
                              {w0.z,w1.z,w2.z,w3.z},{w0.w,w1.w,w2.w,w3.w}};
#pragma unroll
            for (int cc = 0; cc < 4; ++cc) {
                float4 zr = *(float4*)&zt[(c4 * 4 + cc) * 68 + il];
                float zz[4] = {zr.x, zr.y, zr.z, zr.w};
#pragma unroll
                for (int ri = 0; ri < 4; ++ri)
#pragma unroll
                    for (int oi = 0; oi < 4; ++oi)
                        acc[ri][oi] = fmaf(zz[ri], ww[cc][oi], acc[ri][oi]);
            }
        }
#pragma unroll
        for (int ri = 0; ri < 4; ++ri) {
            uint2 pk = make_uint2(pack2bf(acc[ri][0], acc[ri][1]),
                                  pack2bf(acc[ri][2], acc[ri][3]));
            *(uint2*)&qb[((size_t)b * N_ + i0 + il + ri) * CD_ + o0 + og * 4] = pk;
        }
    } else {
        const float* zsrc = zm + (size_t)b * CM_ * N_ + i0;
#pragma unroll
        for (int rep = 0; rep < 4; ++rep) {
            int idx = tid + rep * 256;
            int c = idx >> 4, f = idx & 15;
            *(float4*)&zt[c * 68 + f * 4] = *(const float4*)&zsrc[(size_t)c * N_ + f * 4];
        }
        __syncthreads();
        const float* kr0 = Wk + (size_t)(o0 + og * 4 + 0) * CM_;
        const float* kr1 = Wk + (size_t)(o0 + og * 4 + 1) * CM_;
        const float* kr2 = Wk + (size_t)(o0 + og * 4 + 2) * CM_;
        const float* kr3 = Wk + (size_t)(o0 + og * 4 + 3) * CM_;
        const float* vr0 = Wv + (size_t)(o0 + og * 4 + 0) * CM_;
        const float* vr1 = Wv + (size_t)(o0 + og * 4 + 1) * CM_;
        const float* vr2 = Wv + (size_t)(o0 + og * 4 + 2) * CM_;
        const float* vr3 = Wv + (size_t)(o0 + og * 4 + 3) * CM_;
        float ak[4][4], av[4][4];
#pragma unroll
        for (int oi = 0; oi < 4; ++oi) {
            float bk0 = bk[o0 + og * 4 + oi], bv0 = bv[o0 + og * 4 + oi];
#pragma unroll
            for (int ri = 0; ri < 4; ++ri) { ak[ri][oi] = bk0; av[ri][oi] = bv0; }
        }
        for (int c4 = 0; c4 < 16; ++c4) {
            float4 k0 = *(const float4*)&kr0[c4 * 4];
            float4 k1 = *(const float4*)&kr1[c4 * 4];
            float4 k2 = *(const float4*)&kr2[c4 * 4];
            float4 k3 = *(const float4*)&kr3[c4 * 4];
            float4 v0 = *(const float4*)&vr0[c4 * 4];
            float4 v1 = *(const float4*)&vr1[c4 * 4];
            float4 v2 = *(const float4*)&vr2[c4 * 4];
            float4 v3 = *(const float4*)&vr3[c4 * 4];
            float kk[4][4] = {{k0.x,k1.x,k2.x,k3.x},{k0.y,k1.y,k2.y,k3.y},
                              {k0.z,k1.z,k2.z,k3.z},{k0.w,k1.w,k2.w,k3.w}};
            float vv[4][4] = {{v0.x,v1.x,v2.x,v3.x},{v0.y,v1.y,v2.y,v3.y},
                              {v0.z,v1.z,v2.z,v3.z},{v0.w,v1.w,v2.w,v3.w}};
#pragma unroll
            for (int cc = 0; cc < 4; ++cc) {
                float4 zr = *(float4*)&zt[(c4 * 4 + cc) * 68 + il];
                float zz[4] = {zr.x, zr.y, zr.z, zr.w};
#pragma unroll
                for (int ri = 0; ri < 4; ++ri)
#pragma unroll
                    for (int oi = 0; oi < 4; ++oi) {
                        ak[ri][oi] = fmaf(zz[ri], kk[cc][oi], ak[ri][oi]);
                        av[ri][oi] = fmaf(zz[ri], vv[cc][oi], av[ri][oi]);
                    }
            }
        }
#pragma unroll
        for (int ri = 0; ri < 4; ++ri) {
            uint2 pk = make_uint2(pack2bf(ak[ri][0], ak[ri][1]),
                                  pack2bf(ak[ri][2], ak[ri][3]));
            *(uint2*)&kb[((size_t)b * N_ + i0 + il + ri) * CD_ + o0 + og * 4] = pk;
        }
        const size_t vbase = (size_t)b * CD_ * N_;
#pragma unroll
        for (int oi = 0; oi < 4; ++oi) {
            uint2 pk = make_uint2(pack2bf(av[0][oi], av[1][oi]),
                                  pack2bf(av[2][oi], av[3][oi]));
            *(uint2*)&vb[vbase + (size_t)(o0 + og * 4 + oi) * N_ + i0 + il] = pk;
        }
    }
}

// ---------------- flash, 4 waves/block share K dbuf, i-tile=128, split-j ----------------
// block = 256 threads (4 waves); wave w owns i-strip i0 + w*32 .. +31.
// K double-buffered in LDS via global_load_lds (XOR-swizzled); V direct from L2.
// P->bf16 via v_cvt_pk_bf16_f32; PV B-frags via v_permlane32_swap_b32.
__global__ __launch_bounds__(256, 2)
void flash5(const short* __restrict__ qb, const short* __restrict__ kb,
            const short* __restrict__ vb, float* __restrict__ Op,
            float* __restrict__ ml)
{
    __shared__ short Ks[2][64 * 128];    // 2 x 16 KB, XOR-swizzled c16 ^= (j&15)

    const int tid   = threadIdx.x;
    const int wid   = tid >> 6;                  // 0..3
    const int lane  = tid & 63;
    const int m5    = lane & 31;
    const int h     = lane >> 5;
    const int m15   = m5 & 15;
    const int l4r   = lane >> 4;                 // 0..3
    const int pc    = (lane & 15) ^ l4r;         // staging swizzle lane-const

    const int bid = blockIdx.x;
    const int s   = bid % SEG_;
    const int bIt = bid / SEG_;                  // 0..99
    const int b   = bIt >= NIT_ ? 1 : 0;
    const int it  = bIt - b * NIT_;
    const int i0  = it * 128;
    const int jbase = s * JSEG_;

    const short* qbp = qb + (size_t)b * N_ * CD_;
    const short* kbp = kb + (size_t)b * N_ * CD_;
    const short* vbp = vb + (size_t)b * CD_ * N_;

    // Q B-frags in registers (row = this lane's i)
    const int irow = i0 + wid * 32 + m5;
    bf16x8 qf[8];
#pragma unroll
    for (int kw = 0; kw < 8; ++kw)
        qf[kw] = *(const bf16x8*)&qbp[(size_t)irow * CD_ + kw * 16 + h * 8];

    f32x16 acc[4];
#pragma unroll
    for (int os = 0; os < 4; ++os)
#pragma unroll
        for (int r2 = 0; r2 < 16; ++r2) acc[os][r2] = 0.f;
    float lrun = 0.f;

    // prologue: stage tile 0 into buf 0 (16 loads split 4 per wave)
#pragma unroll
    for (int tt = 0; tt < 4; ++tt) {
        int t = wid * 4 + tt;
        int st = (4 * t) & 15;
        const char* g = (const char*)kbp + (size_t)(jbase + 4 * t + l4r) * 256
                        + ((pc ^ st) << 4);
        __builtin_amdgcn_global_load_lds(
            (const __attribute__((address_space(1))) void*)g,
            (__attribute__((address_space(3))) void*)&Ks[0][t * 512], 16, 0, 0);
    }
    __syncthreads();

    for (int jti = 0; jti < NJT_; ++jti) {
        const int jt  = jbase + jti * JT_;
        const int cur = jti & 1;
        // prefetch next K tile into the other buffer
        if (jti + 1 < NJT_) {
            const int jn = jt + JT_;
#pragma unroll
            for (int tt = 0; tt < 4; ++tt) {
                int t = wid * 4 + tt;
                int st = (4 * t) & 15;
                const char* g = (const char*)kbp + (size_t)(jn + 4 * t + l4r) * 256
                                + ((pc ^ st) << 4);
                __builtin_amdgcn_global_load_lds(
                    (const __attribute__((address_space(1))) void*)g,
                    (__attribute__((address_space(3))) void*)&Ks[1 - cur][t * 512], 16, 0, 0);
            }
        }

        unsigned fr[4][4];
#pragma unroll
        for (int jc = 0; jc < 2; ++jc) {
            // QK^T: D[j][i], this wave: j = jc*32 + regs, i = m5
            f32x16 sacc;
#pragma unroll
            for (int r2 = 0; r2 < 16; ++r2) sacc[r2] = 0.f;
#pragma unroll
            for (int kw = 0; kw < 8; ++kw) {
                int c16 = (2 * kw + h) ^ m15;
                bf16x8 kf = *(const bf16x8*)&Ks[cur][(jc * 32 + m5) * 128 + c16 * 8];
                sacc = __builtin_amdgcn_mfma_f32_32x32x16_bf16(kf, qf[kw], sacc, 0, 0, 0);
            }
            // exp(s - 25), pack to bf16 pairs (1-op cvt_pk), accumulate l
            unsigned pk[8];
#pragma unroll
            for (int p = 0; p < 8; ++p) {
                float e0 = __expf(sacc[2 * p]     - 25.f);
                float e1 = __expf(sacc[2 * p + 1] - 25.f);
                lrun += e0 + e1;
                pk[p] = cvtpk_bf16(e0, e1);
            }
            // B-frags for PV via permlane32_swap:
            //   swap(A=pk[4X+w], B=pk[4X+2+w]) -> {fr[w], fr[2+w]}
#pragma unroll
            for (int X = 0; X < 2; ++X) {
                auto r0 = __builtin_amdgcn_permlane32_swap(
                              pk[4 * X],     pk[4 * X + 2], false, false);
                auto r1 = __builtin_amdgcn_permlane32_swap(
                              pk[4 * X + 1], pk[4 * X + 3], false, false);
                fr[2 * jc + X][0] = (unsigned)r0[0];
                fr[2 * jc + X][1] = (unsigned)r1[0];
                fr[2 * jc + X][2] = (unsigned)r0[1];
                fr[2 * jc + X][3] = (unsigned)r1[1];
            }
        }
        // PV: O[o][i] += V[o][j] P[j][i]
#pragma unroll
        for (int kc = 0; kc < 4; ++kc) {
            union { unsigned u[4]; bf16x8 v; } pf;
#pragma unroll
            for (int u = 0; u < 4; ++u) pf.u[u] = fr[kc][u];
#pragma unroll
            for (int os = 0; os < 4; ++os) {
                bf16x8 vf = *(const bf16x8*)&vbp[(size_t)(os * 32 + m5) * N_
                                                 + jt + kc * 16 + 8 * h];
                acc[os] = __builtin_amdgcn_mfma_f32_32x32x16_bf16(vf, pf.v, acc[os], 0, 0, 0);
            }
        }
        __syncthreads();   // drains prefetch (vmcnt0) + protects dbuf swap
    }

    // l per row
    float lt = lrun + __shfl_xor(lrun, 32);
    if (h == 0) ml[((size_t)bIt * SEG_ + s) * 128 + wid * 32 + m5] = lt;

    // epilogue: two rounds of 64 rows; O -> LDS (swizzled) -> coalesced global
    float* Of = (float*)&Ks[0][0];     // 8192 f32 = 32 KB, rows [i][32 quads]
    float* opb = Op + ((size_t)bIt * SEG_ + s) * (128 * CD_);
#pragma unroll
    for (int r = 0; r < 2; ++r) {
        __syncthreads();               // Of free (prev round copied / main loop done)
        if ((wid >> 1) == r) {
            const int il_ = (wid & 1) * 32 + m5;
#pragma unroll
            for (int os = 0; os < 4; ++os) {
#pragma unroll
                for (int g = 0; g < 4; ++g) {
                    int q = os * 8 + g * 2 + h;
                    int p = q ^ m5;
                    *(float4*)&Of[il_ * 128 + p * 4] =
                        make_float4(acc[os][4 * g], acc[os][4 * g + 1],
                                    acc[os][4 * g + 2], acc[os][4 * g + 3]);
                }
            }
        }
        __syncthreads();
#pragma unroll
        for (int u = 0; u < 8; ++u) {
            int G = u * 256 + tid;          // float4 index within 64x128 block
            int i = G >> 5;
            int q = tid & 31;
            int p = q ^ (i & 31);
            *(float4*)&opb[(size_t)r * 64 * CD_ + (size_t)G * 4] =
                *(float4*)&Of[i * 128 + p * 4];
        }
    }
}

// ---------------- combine SEG_ partials -> out = gamma*SumO/Suml + z_hsi ----------------
// one block per 64-row tile; flash tile = 128 rows -> bIt128 = bId>>1, half = bId&1
__global__ __launch_bounds__(256, 2)
void combine2(const float* __restrict__ Op, const float* __restrict__ ml,
              const float* __restrict__ z_hsi, const float* __restrict__ gamma,
              float* __restrict__ out)
{
    __shared__ float T[CD_ * 68];
    __shared__ float fbuf[64];
    const int tid = threadIdx.x;
    const int bId = blockIdx.x;          // 0..199
    const int b  = bId / 100;
    const int it = bId % 100;
    const int i0 = it * 64;
    const int bIt128 = bId >> 1;
    const int half   = bId & 1;
    const float g = gamma[0];

    if (tid < 64) {
        float den = 0.f;
#pragma unroll
        for (int s2 = 0; s2 < SEG_; ++s2)
            den += ml[((size_t)bIt128 * SEG_ + s2) * 128 + half * 64 + tid];
        fbuf[tid] = g / den;
    }
    __syncthreads();
    {
        const int i = tid >> 2, oc = tid & 3;
        const float f = fbuf[i];
        const float* base = Op + ((size_t)bIt128 * SEG_ * 128 + half * 64 + i) * CD_;
#pragma unroll
        for (int och = 0; och < 8; ++och) {
            int o4 = oc * 32 + och * 4;
            float4 a = *(const float4*)&base[o4];
#pragma unroll
            for (int s2 = 1; s2 < SEG_; ++s2) {
                float4 t = *(const float4*)&base[(size_t)s2 * 128 * CD_ + o4];
                a.x += t.x; a.y += t.y; a.z += t.z; a.w += t.w;
            }
            T[(o4 + 0) * 68 + i] = a.x * f;
            T[(o4 + 1) * 68 + i] = a.y * f;
            T[(o4 + 2) * 68 + i] = a.z * f;
            T[(o4 + 3) * 68 + i] = a.w * f;
        }
    }
    __syncthreads();
    {
        const int o = tid >> 1, ih = (tid & 1) * 32;
        const size_t gbase = ((size_t)b * CD_ + o) * N_ + i0 + ih;
#pragma unroll
        for (int rr = 0; rr < 8; ++rr) {
            int i4 = ih + rr * 4;
            float4 t  = *(float4*)&T[o * 68 + i4];
            float4 z4 = *(const float4*)&z_hsi[gbase + rr * 4];
            *(float4*)&out[gbase + rr * 4] =
                make_float4(t.x + z4.x, t.y + z4.y, t.z + z4.z, t.w + z4.w);
        }
    }
}

extern "C" void kernel_launch(void* const* d_in, const int* in_sizes, int n_in,
                              void* d_out, int out_size, void* d_ws, size_t ws_size,
                              hipStream_t stream) {
    const float* z_hsi = (const float*)d_in[0];
    const float* z_msi = (const float*)d_in[1];
    const float* Wq    = (const float*)d_in[2];
    const float* bq    = (const float*)d_in[3];
    const float* Wk    = (const float*)d_in[4];
    const float* bk    = (const float*)d_in[5];
    const float* Wv    = (const float*)d_in[6];
    const float* bv    = (const float*)d_in[7];
    const float* gamma = (const float*)d_in[8];
    float* out = (float*)d_out;

    const size_t nqb = (size_t)B_ * N_ * CD_;          // 1,638,400 bf16 each
    short* qb = (short*)d_ws;
    short* kb = qb + nqb;
    short* vb = kb + nqb;
    float* Op = (float*)(vb + nqb);                    // 100*10*128*128 f32 = 65.5 MB
    float* ml = Op + (size_t)100 * SEG_ * 128 * CD_;   // 100*10*128 f32

    proj2<<<dim3(800), dim3(256), 0, stream>>>(z_hsi, z_msi, Wq, bq, Wk, bk, Wv, bv,
                                               qb, kb, vb);
    flash5<<<dim3(100 * SEG_), dim3(256), 0, stream>>>(qb, kb, vb, Op, ml);
    combine2<<<dim3(200), dim3(256), 0, stream>>>(Op, ml, z_hsi, gamma, out);
}

// Round 3
// 153.250 us; speedup vs baseline: 1.5649x; 1.5649x over previous
//
#include <hip/hip_runtime.h>
#include <hip/hip_bf16.h>

#define B_    2
#define N_    6400
#define CD_   128
#define CM_   64
#define SEG_  5
#define JSEG_ (N_ / SEG_)    // 1280
#define JT_   64
#define NJT_  (JSEG_ / JT_)  // 20
#define NIT_  50             // i-tiles of 128 per batch (flash)

typedef __attribute__((ext_vector_type(8)))  short bf16x8;
typedef __attribute__((ext_vector_type(16))) float f32x16;

static __device__ __forceinline__ unsigned pack2bf(float a, float b) {
    // {lo16: bf16(a), hi16: bf16(b)} via round-half-up + byte-perm
    union { float f; unsigned u; } x, y; x.f = a; y.f = b;
    return __builtin_amdgcn_perm(y.u + 0x8000u, x.u + 0x8000u, 0x07060302u);
}

static __device__ __forceinline__ unsigned cvtpk_bf16(float a, float b) {
    // {lo16: bf16(a), hi16: bf16(b)}, RNE — single VALU op
    unsigned r;
    asm("v_cvt_pk_bf16_f32 %0, %1, %2" : "=v"(r) : "v"(a), "v"(b));
    return r;
}

// ---------------- fused projections ----------------
// blocks [0,400): q from z_hsi (C=128); [400,800): k,v from z_msi (C=64)
// qb[b][i][o], kb[b][j][o], vb[b][o][j]  (bf16)
__global__ __launch_bounds__(256, 4)
void proj2(const float* __restrict__ zh, const float* __restrict__ zm,
           const float* __restrict__ Wq, const float* __restrict__ bq,
           const float* __restrict__ Wk, const float* __restrict__ bk,
           const float* __restrict__ Wv, const float* __restrict__ bv,
           short* __restrict__ qb, short* __restrict__ kb, short* __restrict__ vb)
{
    __shared__ float zt[128 * 68];   // [c][i], stride 68 (16B-aligned rows)
    const int tid = threadIdx.x;
    int bid = blockIdx.x;
    const int qmode = bid < 400;
    if (!qmode) bid -= 400;
    const int b  = bid / 200;
    const int r  = bid % 200;
    const int i0 = (r >> 1) * 64;
    const int o0 = (r & 1) * 64;
    const int ig = tid & 15, og = tid >> 4;
    const int il = ig * 4;

    if (qmode) {
        const float* zsrc = zh + (size_t)b * CD_ * N_ + i0;
#pragma unroll
        for (int rep = 0; rep < 8; ++rep) {
            int idx = tid + rep * 256;
            int c = idx >> 4, f = idx & 15;
            *(float4*)&zt[c * 68 + f * 4] = *(const float4*)&zsrc[(size_t)c * N_ + f * 4];
        }
        __syncthreads();
        const float* wr0 = Wq + (size_t)(o0 + og * 4 + 0) * CD_;
        const float* wr1 = Wq + (size_t)(o0 + og * 4 + 1) * CD_;
        const float* wr2 = Wq + (size_t)(o0 + og * 4 + 2) * CD_;
        const float* wr3 = Wq + (size_t)(o0 + og * 4 + 3) * CD_;
        float acc[4][4];
#pragma unroll
        for (int oi = 0; oi < 4; ++oi) {
            float bb = bq[o0 + og * 4 + oi];
#pragma unroll
            for (int ri = 0; ri < 4; ++ri) acc[ri][oi] = bb;
        }
        for (int c4 = 0; c4 < 32; ++c4) {
            float4 w0 = *(const float4*)&wr0[c4 * 4];
            float4 w1 = *(const float4*)&wr1[c4 * 4];
            float4 w2 = *(const float4*)&wr2[c4 * 4];
            float4 w3 = *(const float4*)&wr3[c4 * 4];
            float ww[4][4] = {{w0.x,w1.x,w2.x,w3.x},{w0.y,w1.y,w2.y,w3.y},
                              {w0.z,w1.z,w2.z,w3.z},{w0.w,w1.w,w2.w,w3.w}};
#pragma unroll
            for (int cc = 0; cc < 4; ++cc) {
                float4 zr = *(float4*)&zt[(c4 * 4 + cc) * 68 + il];
                float zz[4] = {zr.x, zr.y, zr.z, zr.w};
#pragma unroll
                for (int ri = 0; ri < 4; ++ri)
#pragma unroll
                    for (int oi = 0; oi < 4; ++oi)
                        acc[ri][oi] = fmaf(zz[ri], ww[cc][oi], acc[ri][oi]);
            }
        }
#pragma unroll
        for (int ri = 0; ri < 4; ++ri) {
            uint2 pk = make_uint2(pack2bf(acc[ri][0], acc[ri][1]),
                                  pack2bf(acc[ri][2], acc[ri][3]));
            *(uint2*)&qb[((size_t)b * N_ + i0 + il + ri) * CD_ + o0 + og * 4] = pk;
        }
    } else {
        const float* zsrc = zm + (size_t)b * CM_ * N_ + i0;
#pragma unroll
        for (int rep = 0; rep < 4; ++rep) {
            int idx = tid + rep * 256;
            int c = idx >> 4, f = idx & 15;
            *(float4*)&zt[c * 68 + f * 4] = *(const float4*)&zsrc[(size_t)c * N_ + f * 4];
        }
        __syncthreads();
        const float* kr0 = Wk + (size_t)(o0 + og * 4 + 0) * CM_;
        const float* kr1 = Wk + (size_t)(o0 + og * 4 + 1) * CM_;
        const float* kr2 = Wk + (size_t)(o0 + og * 4 + 2) * CM_;
        const float* kr3 = Wk + (size_t)(o0 + og * 4 + 3) * CM_;
        const float* vr0 = Wv + (size_t)(o0 + og * 4 + 0) * CM_;
        const float* vr1 = Wv + (size_t)(o0 + og * 4 + 1) * CM_;
        const float* vr2 = Wv + (size_t)(o0 + og * 4 + 2) * CM_;
        const float* vr3 = Wv + (size_t)(o0 + og * 4 + 3) * CM_;
        float ak[4][4], av[4][4];
#pragma unroll
        for (int oi = 0; oi < 4; ++oi) {
            float bk0 = bk[o0 + og * 4 + oi], bv0 = bv[o0 + og * 4 + oi];
#pragma unroll
            for (int ri = 0; ri < 4; ++ri) { ak[ri][oi] = bk0; av[ri][oi] = bv0; }
        }
        for (int c4 = 0; c4 < 16; ++c4) {
            float4 k0 = *(const float4*)&kr0[c4 * 4];
            float4 k1 = *(const float4*)&kr1[c4 * 4];
            float4 k2 = *(const float4*)&kr2[c4 * 4];
            float4 k3 = *(const float4*)&kr3[c4 * 4];
            float4 v0 = *(const float4*)&vr0[c4 * 4];
            float4 v1 = *(const float4*)&vr1[c4 * 4];
            float4 v2 = *(const float4*)&vr2[c4 * 4];
            float4 v3 = *(const float4*)&vr3[c4 * 4];
            float kk[4][4] = {{k0.x,k1.x,k2.x,k3.x},{k0.y,k1.y,k2.y,k3.y},
                              {k0.z,k1.z,k2.z,k3.z},{k0.w,k1.w,k2.w,k3.w}};
            float vv[4][4] = {{v0.x,v1.x,v2.x,v3.x},{v0.y,v1.y,v2.y,v3.y},
                              {v0.z,v1.z,v2.z,v3.z},{v0.w,v1.w,v2.w,v3.w}};
#pragma unroll
            for (int cc = 0; cc < 4; ++cc) {
                float4 zr = *(float4*)&zt[(c4 * 4 + cc) * 68 + il];
                float zz[4] = {zr.x, zr.y, zr.z, zr.w};
#pragma unroll
                for (int ri = 0; ri < 4; ++ri)
#pragma unroll
                    for (int oi = 0; oi < 4; ++oi) {
                        ak[ri][oi] = fmaf(zz[ri], kk[cc][oi], ak[ri][oi]);
                        av[ri][oi] = fmaf(zz[ri], vv[cc][oi], av[ri][oi]);
                    }
            }
        }
#pragma unroll
        for (int ri = 0; ri < 4; ++ri) {
            uint2 pk = make_uint2(pack2bf(ak[ri][0], ak[ri][1]),
                                  pack2bf(ak[ri][2], ak[ri][3]));
            *(uint2*)&kb[((size_t)b * N_ + i0 + il + ri) * CD_ + o0 + og * 4] = pk;
        }
        const size_t vbase = (size_t)b * CD_ * N_;
#pragma unroll
        for (int oi = 0; oi < 4; ++oi) {
            uint2 pk = make_uint2(pack2bf(av[0][oi], av[1][oi]),
                                  pack2bf(av[2][oi], av[3][oi]));
            *(uint2*)&vb[vbase + (size_t)(o0 + og * 4 + oi) * N_ + i0 + il] = pk;
        }
    }
}

// ---------------- flash, 4 waves/block, i-tile=128, K AND V staged in LDS ----------------
// block = 256 threads (4 waves); wave w owns i-strip i0 + w*32 .. +31.
// K dbuf: [64 j][128 o] XOR-swizzled c16 ^= (j&15).
// V dbuf: [128 o][64 j] chunk-swizzled slot = o*8 + (c8 ^ (o&7)); staged with
//   pre-swizzled global source (rule: swizzle both sides), read as A-frags from LDS.
// This replaces the per-wave 12.8KB-stride V gather (64 lines/load) with one
// coalesced 16KB stage per tile per block (16x fewer L2 bytes).
__global__ __launch_bounds__(256, 2)
void flash6(const short* __restrict__ qb, const short* __restrict__ kb,
            const short* __restrict__ vb, float* __restrict__ Op,
            float* __restrict__ ml)
{
    __shared__ short Ks[2][64 * 128];    // 2 x 16 KB
    __shared__ short Vs[2][128 * 64];    // 2 x 16 KB

    const int tid   = threadIdx.x;
    const int wid   = tid >> 6;                  // 0..3
    const int lane  = tid & 63;
    const int m5    = lane & 31;
    const int h     = lane >> 5;
    const int m15   = m5 & 15;
    const int l4r   = lane >> 4;                 // 0..3
    const int pc    = (lane & 15) ^ l4r;         // K staging swizzle lane-const

    // V staging lane constants: lane l fetches chunk (o = t*8 + (l>>3), c8 = (l&7)^((l>>3)&7))
    const int vrow = lane >> 3;                  // 0..7
    const int vc8  = (lane & 7) ^ (vrow & 7);
    const int voff = vrow * (N_ * 2) + vc8 * 16; // byte offset within 8-row group

    const int bid = blockIdx.x;
    const int s   = bid % SEG_;
    const int bIt = bid / SEG_;                  // 0..99
    const int b   = bIt >= NIT_ ? 1 : 0;
    const int it  = bIt - b * NIT_;
    const int i0  = it * 128;
    const int jbase = s * JSEG_;

    const short* qbp = qb + (size_t)b * N_ * CD_;
    const short* kbp = kb + (size_t)b * N_ * CD_;
    const char*  vstage = (const char*)(vb + (size_t)b * CD_ * N_) + voff;

    // Q B-frags in registers (row = this lane's i)
    const int irow = i0 + wid * 32 + m5;
    bf16x8 qf[8];
#pragma unroll
    for (int kw = 0; kw < 8; ++kw)
        qf[kw] = *(const bf16x8*)&qbp[(size_t)irow * CD_ + kw * 16 + h * 8];

    f32x16 acc[4];
#pragma unroll
    for (int os = 0; os < 4; ++os)
#pragma unroll
        for (int r2 = 0; r2 < 16; ++r2) acc[os][r2] = 0.f;
    float lrun = 0.f;

    // prologue: stage K0 and V0 into buf 0 (4 loads each per wave)
#pragma unroll
    for (int tt = 0; tt < 4; ++tt) {
        int t = wid * 4 + tt;
        int st = (4 * t) & 15;
        const char* g = (const char*)kbp + (size_t)(jbase + 4 * t + l4r) * 256
                        + ((pc ^ st) << 4);
        __builtin_amdgcn_global_load_lds(
            (const __attribute__((address_space(1))) void*)g,
            (__attribute__((address_space(3))) void*)&Ks[0][t * 512], 16, 0, 0);
    }
#pragma unroll
    for (int tt = 0; tt < 4; ++tt) {
        int t = wid * 4 + tt;
        const char* g = vstage + (size_t)(t * 8) * (N_ * 2) + (size_t)jbase * 2;
        __builtin_amdgcn_global_load_lds(
            (const __attribute__((address_space(1))) void*)g,
            (__attribute__((address_space(3))) void*)&Vs[0][t * 512], 16, 0, 0);
    }
    __syncthreads();

    for (int jti = 0; jti < NJT_; ++jti) {
        const int jt  = jbase + jti * JT_;
        const int cur = jti & 1;
        // prefetch next K,V tiles into the other buffers
        if (jti + 1 < NJT_) {
            const int jn = jt + JT_;
#pragma unroll
            for (int tt = 0; tt < 4; ++tt) {
                int t = wid * 4 + tt;
                int st = (4 * t) & 15;
                const char* g = (const char*)kbp + (size_t)(jn + 4 * t + l4r) * 256
                                + ((pc ^ st) << 4);
                __builtin_amdgcn_global_load_lds(
                    (const __attribute__((address_space(1))) void*)g,
                    (__attribute__((address_space(3))) void*)&Ks[1 - cur][t * 512], 16, 0, 0);
            }
#pragma unroll
            for (int tt = 0; tt < 4; ++tt) {
                int t = wid * 4 + tt;
                const char* g = vstage + (size_t)(t * 8) * (N_ * 2) + (size_t)jn * 2;
                __builtin_amdgcn_global_load_lds(
                    (const __attribute__((address_space(1))) void*)g,
                    (__attribute__((address_space(3))) void*)&Vs[1 - cur][t * 512], 16, 0, 0);
            }
        }

        unsigned fr[4][4];
#pragma unroll
        for (int jc = 0; jc < 2; ++jc) {
            // QK^T: D[j][i], this wave: j = jc*32 + regs, i = m5
            f32x16 sacc;
#pragma unroll
            for (int r2 = 0; r2 < 16; ++r2) sacc[r2] = 0.f;
#pragma unroll
            for (int kw = 0; kw < 8; ++kw) {
                int c16 = (2 * kw + h) ^ m15;
                bf16x8 kf = *(const bf16x8*)&Ks[cur][(jc * 32 + m5) * 128 + c16 * 8];
                sacc = __builtin_amdgcn_mfma_f32_32x32x16_bf16(kf, qf[kw], sacc, 0, 0, 0);
            }
            // exp(s - 25), pack to bf16 pairs (1-op cvt_pk), accumulate l
            unsigned pk[8];
#pragma unroll
            for (int p = 0; p < 8; ++p) {
                float e0 = __expf(sacc[2 * p]     - 25.f);
                float e1 = __expf(sacc[2 * p + 1] - 25.f);
                lrun += e0 + e1;
                pk[p] = cvtpk_bf16(e0, e1);
            }
            // B-frags for PV via permlane32_swap:
            //   swap(A=pk[4X+w], B=pk[4X+2+w]) -> {fr[w], fr[2+w]}
#pragma unroll
            for (int X = 0; X < 2; ++X) {
                auto r0 = __builtin_amdgcn_permlane32_swap(
                              pk[4 * X],     pk[4 * X + 2], false, false);
                auto r1 = __builtin_amdgcn_permlane32_swap(
                              pk[4 * X + 1], pk[4 * X + 3], false, false);
                fr[2 * jc + X][0] = (unsigned)r0[0];
                fr[2 * jc + X][1] = (unsigned)r1[0];
                fr[2 * jc + X][2] = (unsigned)r0[1];
                fr[2 * jc + X][3] = (unsigned)r1[1];
            }
        }
        // PV: O[o][i] += V[o][j] P[j][i] ; V A-frags from LDS (swizzled)
#pragma unroll
        for (int kc = 0; kc < 4; ++kc) {
            union { unsigned u[4]; bf16x8 v; } pf;
#pragma unroll
            for (int u = 0; u < 4; ++u) pf.u[u] = fr[kc][u];
#pragma unroll
            for (int os = 0; os < 4; ++os) {
                int o = os * 32 + m5;
                int q = (kc * 2 + h) ^ (m5 & 7);
                bf16x8 vf = *(const bf16x8*)&Vs[cur][o * 64 + q * 8];
                acc[os] = __builtin_amdgcn_mfma_f32_32x32x16_bf16(vf, pf.v, acc[os], 0, 0, 0);
            }
        }
        __syncthreads();   // drains prefetch (vmcnt0) + protects dbuf swap
    }

    // l per row
    float lt = lrun + __shfl_xor(lrun, 32);
    if (h == 0) ml[((size_t)bIt * SEG_ + s) * 128 + wid * 32 + m5] = lt;

    // epilogue: two rounds of 64 rows; O -> LDS (swizzled) -> coalesced global
    float* Of = (float*)&Ks[0][0];     // 8192 f32 = 32 KB (both K buffers)
    float* opb = Op + ((size_t)bIt * SEG_ + s) * (128 * CD_);
#pragma unroll
    for (int r = 0; r < 2; ++r) {
        __syncthreads();               // Of free (prev round copied / main loop done)
        if ((wid >> 1) == r) {
            const int il_ = (wid & 1) * 32 + m5;
#pragma unroll
            for (int os = 0; os < 4; ++os) {
#pragma unroll
                for (int g = 0; g < 4; ++g) {
                    int q = os * 8 + g * 2 + h;
                    int p = q ^ m5;
                    *(float4*)&Of[il_ * 128 + p * 4] =
                        make_float4(acc[os][4 * g], acc[os][4 * g + 1],
                                    acc[os][4 * g + 2], acc[os][4 * g + 3]);
                }
            }
        }
        __syncthreads();
#pragma unroll
        for (int u = 0; u < 8; ++u) {
            int G = u * 256 + tid;          // float4 index within 64x128 block
            int i = G >> 5;
            int q = tid & 31;
            int p = q ^ (i & 31);
            *(float4*)&opb[(size_t)r * 64 * CD_ + (size_t)G * 4] =
                *(float4*)&Of[i * 128 + p * 4];
        }
    }
}

// ---------------- combine SEG_ partials -> out = gamma*SumO/Suml + z_hsi ----------------
// 400 blocks x 32 rows (flash tile = 128 rows -> 4 blocks per tile)
__global__ __launch_bounds__(256, 4)
void combine3(const float* __restrict__ Op, const float* __restrict__ ml,
              const float* __restrict__ z_hsi, const float* __restrict__ gamma,
              float* __restrict__ out)
{
    __shared__ float T[CD_ * 36];        // [o][i(32)+pad]
    __shared__ float fbuf[32];
    const int tid = threadIdx.x;
    const int blk = blockIdx.x;          // 0..399
    const int bIt = blk >> 2;            // 0..99 (flash tile)
    const int rq  = (blk & 3) * 32;      // row offset within tile
    const int b   = bIt / NIT_;
    const int it  = bIt % NIT_;
    const int i0  = it * 128 + rq;
    const float g = gamma[0];

    if (tid < 32) {
        float den = 0.f;
#pragma unroll
        for (int s2 = 0; s2 < SEG_; ++s2)
            den += ml[((size_t)bIt * SEG_ + s2) * 128 + rq + tid];
        fbuf[tid] = g / den;
    }
    __syncthreads();
    {
        const int i  = tid >> 3;         // 0..31 row
        const int oc = (tid & 7) * 4;    // base o (float4)
        const float f = fbuf[i];
        const float* base = Op + ((size_t)bIt * SEG_ * 128 + rq + i) * CD_ + oc;
#pragma unroll
        for (int c4 = 0; c4 < 4; ++c4) {
            float4 a = *(const float4*)&base[c4 * 32];
#pragma unroll
            for (int s2 = 1; s2 < SEG_; ++s2) {
                float4 t = *(const float4*)&base[(size_t)s2 * 128 * CD_ + c4 * 32];
                a.x += t.x; a.y += t.y; a.z += t.z; a.w += t.w;
            }
            int o = oc + c4 * 32;
            T[(o + 0) * 36 + i] = a.x * f;
            T[(o + 1) * 36 + i] = a.y * f;
            T[(o + 2) * 36 + i] = a.z * f;
            T[(o + 3) * 36 + i] = a.w * f;
        }
    }
    __syncthreads();
    {
        const int o = tid >> 1, ih = (tid & 1) * 16;
        const size_t gbase = ((size_t)b * CD_ + o) * N_ + i0 + ih;
#pragma unroll
        for (int rr = 0; rr < 4; ++rr) {
            float4 t  = *(float4*)&T[o * 36 + ih + rr * 4];
            float4 z4 = *(const float4*)&z_hsi[gbase + rr * 4];
            *(float4*)&out[gbase + rr * 4] =
                make_float4(t.x + z4.x, t.y + z4.y, t.z + z4.z, t.w + z4.w);
        }
    }
}

extern "C" void kernel_launch(void* const* d_in, const int* in_sizes, int n_in,
                              void* d_out, int out_size, void* d_ws, size_t ws_size,
                              hipStream_t stream) {
    const float* z_hsi = (const float*)d_in[0];
    const float* z_msi = (const float*)d_in[1];
    const float* Wq    = (const float*)d_in[2];
    const float* bq    = (const float*)d_in[3];
    const float* Wk    = (const float*)d_in[4];
    const float* bk    = (const float*)d_in[5];
    const float* Wv    = (const float*)d_in[6];
    const float* bv    = (const float*)d_in[7];
    const float* gamma = (const float*)d_in[8];
    float* out = (float*)d_out;

    const size_t nqb = (size_t)B_ * N_ * CD_;          // 1,638,400 bf16 each
    short* qb = (short*)d_ws;
    short* kb = qb + nqb;
    short* vb = kb + nqb;
    float* Op = (float*)(vb + nqb);                    // 100*5*128*128 f32 = 32.8 MB
    float* ml = Op + (size_t)100 * SEG_ * 128 * CD_;   // 100*5*128 f32

    proj2<<<dim3(800), dim3(256), 0, stream>>>(z_hsi, z_msi, Wq, bq, Wk, bk, Wv, bv,
                                               qb, kb, vb);
    flash6<<<dim3(100 * SEG_), dim3(256), 0, stream>>>(qb, kb, vb, Op, ml);
    combine3<<<dim3(400), dim3(256), 0, stream>>>(Op, ml, z_hsi, gamma, out);
}